// Round 5
// baseline (967.361 us; speedup 1.0000x reference)
//
#include <hip/hip_runtime.h>
#include <math.h>

#define B_ 2
#define V_ 8
#define C_ 64
#define HW_ 16384
#define A_ 256
#define P_ 65536
#define CO_ 192
#define CPG_ 24
#define NG_ 8
#define ICP1 224
#define ICP2 192

// workspace layout (bytes)
#define OFF_ACC   0ull
#define SZ_ACC    (2ull*65536*192*4)          // 100,663,296 ; reused for h1pre (bf16) then h2 (bf16)
#define OFF_CNT   (OFF_ACC + SZ_ACC)
#define SZ_CNT    (2ull*3*65536*4)
#define OFF_CTXB  (OFF_CNT + SZ_CNT)          // ctx NHWC bf16, 224-ch padded
#define SZ_CTXB   (2ull*65536*224*2)
#define OFF_H1A   (OFF_CTXB + SZ_CTXB)        // h1 activated, NHWC bf16, 192 ch
#define SZ_H1A    (2ull*65536*192*2)
#define OFF_W1    (OFF_H1A + SZ_H1A)
#define SZ_W1     (9ull*192*224*2)
#define OFF_W2    (OFF_W1 + SZ_W1)
#define SZ_W2     (9ull*192*192*2)
#define OFF_SM    (OFF_W2 + SZ_W2 + 256)

// small-region offsets (within OFF_SM)
#define SM_STATS1 0
#define SM_STATS2 256
#define SM_SCALE  512
#define SM_POOLED 1024
#define SM_GATE   2560
#define SM_RAWU   8192
#define SM_CONFP  532480            // 3*2*65536*4 = 1.5 MB partial conf dots

// d_out offsets (floats)
#define OUT_B    8388608
#define OUT_COV  25165824
#define OUT_UNC  25296896
#define OUT_CONF 25427968

typedef __attribute__((ext_vector_type(4))) float f32x4;
typedef __attribute__((ext_vector_type(8))) short bf16x8;

__device__ __forceinline__ float sigmoidf_(float x){ return 1.f/(1.f+expf(-x)); }
__device__ __forceinline__ float bf2f(unsigned short h){ return __uint_as_float(((unsigned)h)<<16); }
__device__ __forceinline__ unsigned short f2bf(float f){
  unsigned u = __float_as_uint(f);
  return (unsigned short)((u + 0x7fffu + ((u>>16)&1u)) >> 16);
}

__device__ __forceinline__ void gl_lds16(const void* g, void* l){
  __builtin_amdgcn_global_load_lds((const __attribute__((address_space(1))) void*)g,
                                   (__attribute__((address_space(3))) void*)l, 16, 0, 0);
}

// ---------------- K0: weight prep (transpose+pad+bf16) ----------------
__global__ __launch_bounds__(256) void k_prep(const float* __restrict__ c1w,
    const float* __restrict__ c2w, unsigned short* __restrict__ w1p, unsigned short* __restrict__ w2p)
{
  int idx = blockIdx.x*256 + threadIdx.x;
  const int N1 = 9*192*224;
  if (idx < N1){
    int ic = idx % 224; int oc = (idx/224) % 192; int k = idx/(224*192);
    float v = (ic < 194) ? c1w[(size_t)(oc*194+ic)*9 + k] : 0.f;
    w1p[idx] = f2bf(v);
  } else {
    int i2 = idx - N1;
    if (i2 < 9*192*192){
      int ic = i2 % 192; int oc = (i2/192) % 192; int k = i2/(192*192);
      w2p[i2] = f2bf(c2w[(size_t)(oc*192+ic)*9 + k]);
    }
  }
}

// ---------------- K1: fused tri-branch scatter ----------------
__global__ __launch_bounds__(256) void k_fuse(const float* __restrict__ vf,
    const float* __restrict__ uvs, const float* __restrict__ masks,
    const float* __restrict__ wgp, const float* __restrict__ wbp, const float* __restrict__ whp,
    float* __restrict__ acc, float* __restrict__ cnt)
{
  __shared__ __align__(16) float sf[64*65];
  __shared__ int sidx[64];
  __shared__ int svalid[64];
  __shared__ float sw[3];
  int t = threadIdx.x;
  int pix0 = blockIdx.x*64;
  int b   = pix0 / (V_*HW_);
  int rem = pix0 % (V_*HW_);
  int v   = rem / HW_;
  int p2  = rem % HW_;
  size_t vbase = ((size_t)(b*V_+v))*C_*HW_;
  // float4 global loads (1024 xfers), scalar LDS writes keep stride-65 conflict-free reads
  for (int i=0;i<4;i++){
    int f = t + i*256;
    int c = f>>4, px4 = (f&15)*4;
    float4 vv = *(const float4*)&vf[vbase + (size_t)c*HW_ + p2 + px4];
    float* d = &sf[c*65+px4];
    d[0]=vv.x; d[1]=vv.y; d[2]=vv.z; d[3]=vv.w;
  }
  if (t<64){
    const float* u2 = uvs + (((size_t)(b*V_+v))*HW_ + p2 + t)*2;
    float ux = u2[0], uy = u2[1];
    int fin = isfinite(ux) && isfinite(uy);
    float su = fin?ux:0.f, svv = fin?uy:0.f;
    float cu = fminf(fmaxf(su,0.f),1.f);
    float cv = fminf(fmaxf(svv,0.f),1.f);
    int xi = (int)rintf(cu*255.f);
    int yi = (int)rintf((1.f-cv)*255.f);
    sidx[t] = yi*256+xi;
    float m = masks[((size_t)(b*V_+v))*HW_ + p2 + t];
    svalid[t] = (m>0.5f) && fin;
  }
  if (t<3){
    const float* wp = (t==0)?wgp:((t==1)?wbp:whp);
    sw[t] = fmaxf(wp[b*V_+v], 0.f);
  }
  __syncthreads();
  int wave = t>>6, lane = t&63;
  float w0 = sw[0], w1 = sw[1], w2 = sw[2];
  for (int i=0;i<16;i++){
    int px = wave*16+i;
    if (!svalid[px]) continue;
    int bin = sidx[px];
    float val = sf[lane*65+px];
    size_t base = ((size_t)b*P_ + bin)*192;
    if (w0>0.f) atomicAdd(&acc[base + lane],        val*w0);
    if (w1>0.f) atomicAdd(&acc[base + 64 + lane],   val*w1);
    if (w2>0.f) atomicAdd(&acc[base + 128 + lane],  val*w2);
    if (lane<3){
      float wv = sw[lane];
      if (wv>0.f) atomicAdd(&cnt[((size_t)(b*3+lane))*P_ + bin], wv);
    }
  }
}

// ---------------- K2: finalize atlases -> ctx bf16 NHWC, coverage, raw unc, conf partial ----------------
__global__ __launch_bounds__(256) void k_finalize(const float* __restrict__ acc,
      const float* __restrict__ cnt, unsigned short* __restrict__ ctxb,
      float* __restrict__ out_cov, float* __restrict__ raw_unc, int* __restrict__ scale,
      const float* __restrict__ cw, const float* __restrict__ cbias, float* __restrict__ confp)
{
  __shared__ __align__(16) float sv[64*193];
  __shared__ float sc[3][64];
  __shared__ float up[256];
  __shared__ float up3[3][256];
  __shared__ float s_cov[64];
  __shared__ float s_unc[64];
  __shared__ float scw[582];
  int t = threadIdx.x;
  int bin0 = blockIdx.x*64;
  int b = bin0 >> 16;
  int p0 = bin0 & 65535;
  size_t abase = ((size_t)b*P_ + p0)*192;
  for (int f=t; f<582; f+=256) scw[f] = cw[f];
  for (int i=0;i<48;i++){
    int f = t + i*256;
    int bl = f/192, c = f - bl*192;
    sv[bl*193+c] = acc[abase + f];
  }
  if (t<192){
    int br = t>>6, bl = t&63;
    sc[br][bl] = cnt[((size_t)(b*3+br))*P_ + p0 + bl];
  }
  __syncthreads();
  {
    int bl = t>>2, q = t&3;
    float dg = 1.f/fmaxf(sc[0][bl],1.f);
    float db = 1.f/fmaxf(sc[1][bl],1.f);
    float dh = 1.f/fmaxf(sc[2][bl],1.f);
    float s = 0.f;
    for (int j=0;j<16;j++){
      int c = q*16+j;
      float fg = sv[bl*193+c]*dg;
      float fb = sv[bl*193+64+c]*db;
      float fh = sv[bl*193+128+c]*dh;
      sv[bl*193+c]=fg; sv[bl*193+64+c]=fb; sv[bl*193+128+c]=fh;
      float m = (fg+fb+fh)*(1.f/3.f);
      float d0=fg-m, d1=fb-m, d2=fh-m;
      s += d0*d0+d1*d1+d2*d2;
    }
    up[t] = s;
  }
  __syncthreads();
  if (t<64){
    float tot = up[t*4]+up[t*4+1]+up[t*4+2]+up[t*4+3];
    float u = sqrtf(tot*(1.f/192.f));
    float vg = sc[0][t]>0.f?1.f:0.f;
    float vb = sc[1][t]>0.f?1.f:0.f;
    float vh = sc[2][t]>0.f?1.f:0.f;
    float cov = fminf(fmaxf((vg+vb+vh)*(1.f/3.f),0.f),1.f);
    s_cov[t] = cov; s_unc[t] = u;
    out_cov[(size_t)b*P_ + p0 + t] = cov;
    raw_unc[(size_t)b*P_ + p0 + t] = u;
    atomicMax(&scale[b], __float_as_int(u));
  }
  __syncthreads();
  // conf partial dot over 192 feat channels (fp32 — more accurate than bf16 ctx read)
  {
    int bl = t>>2, q = t&3;
    float q0=0.f,q1=0.f,q2=0.f;
    for (int j=0;j<16;j++){
      int c = q*16+j;
      float fg = sv[bl*193+c];
      float fb = sv[bl*193+64+c];
      float fh = sv[bl*193+128+c];
      q0 += fg*scw[c]     + fb*scw[64+c]     + fh*scw[128+c];
      q1 += fg*scw[194+c] + fb*scw[258+c]    + fh*scw[322+c];
      q2 += fg*scw[388+c] + fb*scw[452+c]    + fh*scw[516+c];
    }
    up3[0][t]=q0; up3[1][t]=q1; up3[2][t]=q2;
  }
  __syncthreads();
  if (t<64){
    float cov = s_cov[t];
    #pragma unroll
    for (int o=0;o<3;o++){
      float pdot = up3[o][t*4]+up3[o][t*4+1]+up3[o][t*4+2]+up3[o][t*4+3]
                 + cov*scw[o*194+192] + cbias[o];
      confp[((size_t)(b*3+o))*P_ + p0 + t] = pdot;
    }
  }
  // pack NHWC bf16: 64 px x 28 groups of 8 ch
  for (int f=t; f<1792; f+=256){
    int cg = f % 28, bl = f / 28;
    int c0 = cg*8;
    unsigned short h[8];
    #pragma unroll
    for (int j=0;j<8;j++){
      int c = c0+j;
      float vv;
      if (c < 192)      vv = sv[bl*193+c];
      else if (c==192)  vv = s_cov[bl];
      else if (c==193)  vv = s_unc[bl];
      else              vv = 0.f;
      h[j] = f2bf(vv);
    }
    *(uint4*)&ctxb[((size_t)b*P_ + p0 + bl)*ICP1 + c0] = *(uint4*)h;
  }
}

// ---------------- K3: normalize uncertainty + finish conf ----------------
__global__ __launch_bounds__(256) void k_norm_unc(unsigned short* __restrict__ ctxb,
    const int* __restrict__ scale, const float* __restrict__ raw_unc,
    const float* __restrict__ out_cov, float* __restrict__ out_unc,
    const float* __restrict__ confp, const float* __restrict__ cw, float* __restrict__ out_conf)
{
  int tid = blockIdx.x*256 + threadIdx.x;
  int b = tid >> 16, p = tid & 65535;
  float s = fmaxf(__int_as_float(scale[b]), 1e-6f);
  float u = raw_unc[tid];
  float cov = out_cov[tid];
  float un = fminf(fmaxf(u/s,0.f),1.f)*cov;
  out_unc[tid] = un;
  ctxb[(size_t)tid*ICP1 + 193] = f2bf(un);
  float w0 = cw[193], w1 = cw[387], w2 = cw[581];
  out_conf[((size_t)(b*3+0))*P_ + p] = sigmoidf_(confp[((size_t)(b*3+0))*P_ + p] + w0*un);
  out_conf[((size_t)(b*3+1))*P_ + p] = sigmoidf_(confp[((size_t)(b*3+1))*P_ + p] + w1*un);
  out_conf[((size_t)(b*3+2))*P_ + p] = sigmoidf_(confp[((size_t)(b*3+2))*P_ + p] + w2*un);
}

// ---------------- conv 3x3 via MFMA bf16 implicit GEMM, row-pair, 8-wave role-split ----------------
// v5: 512-thread blocks (8 waves = 4 px-tiles x 2 rows). Each wave: one 64oc x 64px row tile
// (acc = 64 VGPR). LDS unchanged -> 2 blocks/CU but 16 waves/CU (4/SIMD, 2x v4).
// Staging role-split: waves 0-3 issue input rows (vmcnt(4) waits), waves 4-7 issue weights
// (wa=6 instr, wb=3; waits vmcnt(3)/vmcnt(0)). Each role waits only its own counter before
// the shared barrier. Buffer lifetimes identical to v3/v4 schedule. setprio(1) around MFMA.
template<int ICP, int CHUNKS>
__global__ __launch_bounds__(512,4) void k_conv3(const unsigned short* __restrict__ X,
    const unsigned short* __restrict__ Wp, const float* __restrict__ bias, unsigned short* __restrict__ Y,
    double* __restrict__ stats)
{
  __shared__ short s_in[2][258*32];   // 2 x 16512 B
  __shared__ short s_w[576*32];       // 36864 B : rows r = (ky*3+kx)*64 + oc
  __shared__ float sred[2][64];
  __shared__ float gsm[16];
  int t = threadIdx.x;
  // XCD swizzle over 768 blocks: each XCD owns a 16-ypair (32-row) band for all (b,oc)
  int f_ = blockIdx.x + 128*(blockIdx.y + 3*blockIdx.z);
  int xcd = f_ & 7; int g_ = f_ >> 3;
  int ypair = xcd*16 + (g_ & 15);
  int h_  = g_ >> 4;                  // 0..5
  int b   = h_ & 1;
  int oc0 = (h_ >> 1)*64;
  int y0  = ypair*2;                  // 0..254 even
  int w = t>>6, lane = t&63, l15 = lane&15, quad = lane>>4;
  int pxw = (w&3);                    // px tile 0..3
  int rw  = (w>>2);                   // 0 = rowA (y0), 1 = rowB (y0+1)
  bool inputRole = (w < 4);

  f32x4 acc[4][4];
  #pragma unroll
  for (int mt=0;mt<4;mt++){
    float4 bv = *(const float4*)&bias[oc0 + mt*16 + quad*4];
    f32x4 iv; iv.x=bv.x; iv.y=bv.y; iv.z=bv.z; iv.w=bv.w;
    #pragma unroll
    for (int nt=0;nt<4;nt++) acc[mt][nt]=iv;
  }

  const unsigned short* Xb = X + (size_t)b*P_*ICP;

  // zero edge px slots (xi=0, xi=257) in both buffers + stats LDS (waves 0,1 do ds_writes)
  if (t < 128){
    int bufi = t>>6, j = t&63;
    int idx = (j<32) ? j : (257*32 + (j-32));
    s_in[bufi][idx] = 0;
  }
  if (t < 128) sred[t>>6][t&63] = 0.f;
  if (t < 16)  gsm[t] = 0.f;

  // input row stage: threads 0..255 (waves 0-3), 4 gl_lds each, buffer = j2&1
  auto issue_input = [&](int c2, int j2){
    int gy = y0 - 1 + j2;
    gy = min(max(gy,0),255);          // clamp; garbage rows are compute-skipped
    const unsigned short* src = Xb + ((size_t)gy*256)*ICP + c2*32;
    short* dst = &s_in[j2&1][0];
    #pragma unroll
    for (int i=0;i<4;i++){
      int f = t + i*256;              // t in 0..255 here
      int xi = 1 + (f>>2), icq = f&3;
      int icg = icq ^ ((xi>>1)&3);
      gl_lds16(src + (size_t)(xi-1)*ICP + icg*8, dst + 32 + (size_t)f*8);
    }
  };
  // weights ky=0,1 (rows 0..383): threads 256..511, 6 gl_lds each
  auto issue_wa = [&](int c2){
    int ic0n = c2*32;
    int t2 = t - 256;
    #pragma unroll
    for (int i=0;i<6;i++){
      int f = t2 + i*256;
      int oc = (f>>2)&63, icq = f&3;
      int r = (f>>8)*64 + oc;
      int icg = icq ^ ((r>>1)&3);
      gl_lds16(Wp + ((size_t)((f>>8)*192) + oc0 + oc)*ICP + ic0n + icg*8, &s_w[(size_t)f*8]);
    }
  };
  // weights ky=2 (rows 384..575): threads 256..511, 3 gl_lds each
  auto issue_wb = [&](int c2){
    int ic0n = c2*32;
    int t2 = t - 256;
    #pragma unroll
    for (int i=0;i<3;i++){
      int f = t2 + i*256;
      int oc = (f>>2)&63, icq = f&3;
      int r = (6+(f>>8))*64 + oc;
      int icg = icq ^ ((r>>1)&3);
      gl_lds16(Wp + ((size_t)((6+(f>>8))*192) + oc0 + oc)*ICP + ic0n + icg*8, &s_w[(size_t)(1536+f)*8]);
    }
  };

  // prologue (role-split)
  if (inputRole){
    issue_input(0,0);
    issue_input(0,1);
  } else {
    issue_wa(0);
    issue_wb(0);
  }
  asm volatile("s_waitcnt lgkmcnt(0)" ::: "memory");   // edge-zero ds_writes committed (waves 0,1)

  for (int c=0; c<CHUNKS; ++c){
    #pragma unroll
    for (int j=0;j<4;++j){
      // role-specific waits: each wave waits on ITS OWN outstanding loads, then barrier
      if (c==CHUNKS-1 && j==3){
        asm volatile("s_waitcnt vmcnt(0)" ::: "memory");
      } else if (inputRole){
        asm volatile("s_waitcnt vmcnt(4)" ::: "memory");   // current row done, next may fly
      } else {
        if (j==0 || j==1)      asm volatile("s_waitcnt vmcnt(3)" ::: "memory");  // wa done
        else if (j==2)         asm volatile("s_waitcnt vmcnt(0)" ::: "memory");  // wb done
        // j==3: nothing new needed (outstanding = wa' only)
      }
      __builtin_amdgcn_s_barrier();
      __builtin_amdgcn_sched_barrier(0);

      bool doA = (j<=2) && (y0 + j >= 1);          // rowA uses ky=j
      bool doB = (j>=1) && (y0 - 1 + j <= 255);    // rowB uses ky=j-1
      bool mine = rw ? doB : doA;
      int kyr = rw ? (j-1) : j;
      const short* si = &s_in[j&1][0];
      if (mine){
        __builtin_amdgcn_s_setprio(1);
        #pragma unroll
        for (int kx=0;kx<3;kx++){
          bf16x8 Bf[4];
          #pragma unroll
          for (int nt=0;nt<4;nt++){
            int r = pxw*64 + nt*16 + l15 + kx;
            Bf[nt] = *(const bf16x8*)&si[r*32 + ((quad ^ ((r>>1)&3)))*8];
          }
          bf16x8 Af[4];
          #pragma unroll
          for (int mt=0;mt<4;mt++){
            int r = kyr*192 + kx*64 + mt*16 + l15;
            Af[mt] = *(const bf16x8*)&s_w[r*32 + ((quad ^ ((r>>1)&3)))*8];
          }
          #pragma unroll
          for (int mt=0;mt<4;mt++)
            #pragma unroll
            for (int nt=0;nt<4;nt++)
              acc[mt][nt] = __builtin_amdgcn_mfma_f32_16x16x32_bf16(Af[mt], Bf[nt], acc[mt][nt], 0, 0, 0);
        }
        __builtin_amdgcn_s_setprio(0);
      }
      __builtin_amdgcn_s_barrier();
      __builtin_amdgcn_sched_barrier(0);
      // issue slot (role-split; buffer being overwritten was last read in the phase just ended)
      if (inputRole){
        if (!(c==CHUNKS-1 && j>=2))
          issue_input(j>=2 ? c+1 : c, (j+2)&3);
      } else {
        if (j==2 && c+1<CHUNKS) issue_wa(c+1);
        if (j==3 && c+1<CHUNKS) issue_wb(c+1);
      }
    }
  }

  // C-write: this wave's row, bf16 NHWC
  unsigned short* Yb = Y + (size_t)b*P_*192;
  int yrow = y0 + rw;
  #pragma unroll
  for (int mt=0;mt<4;mt++){
    int oc = oc0 + mt*16 + quad*4;
    #pragma unroll
    for (int nt=0;nt<4;nt++){
      int px = pxw*64 + nt*16 + l15;
      f32x4 a = acc[mt][nt];
      ushort4 ha; ha.x=f2bf(a.x); ha.y=f2bf(a.y); ha.z=f2bf(a.z); ha.w=f2bf(a.w);
      *(ushort4*)&Yb[(size_t)(yrow*256+px)*192 + oc] = ha;
    }
  }

  // fused GN stats (fp32 accs): wave-reduce over l15, LDS atomics over waves,
  // per-group LDS reduce, per-group global double atomics.
  #pragma unroll
  for (int mt=0;mt<4;mt++)
    #pragma unroll
    for (int jj=0;jj<4;jj++){
      float v1 = acc[mt][0][jj]+acc[mt][1][jj]+acc[mt][2][jj]+acc[mt][3][jj];
      float v2 = acc[mt][0][jj]*acc[mt][0][jj]+acc[mt][1][jj]*acc[mt][1][jj]
               + acc[mt][2][jj]*acc[mt][2][jj]+acc[mt][3][jj]*acc[mt][3][jj];
      v1 += __shfl_xor(v1,1); v1 += __shfl_xor(v1,2); v1 += __shfl_xor(v1,4); v1 += __shfl_xor(v1,8);
      v2 += __shfl_xor(v2,1); v2 += __shfl_xor(v2,2); v2 += __shfl_xor(v2,4); v2 += __shfl_xor(v2,8);
      if (l15==0){
        int ocl = mt*16 + quad*4 + jj;
        atomicAdd(&sred[0][ocl], v1);
        atomicAdd(&sred[1][ocl], v2);
      }
    }
  __syncthreads();
  if (t < 64){
    int g = (oc0 + t)/24;
    atomicAdd(&gsm[g*2],   sred[0][t]);
    atomicAdd(&gsm[g*2+1], sred[1][t]);
  }
  __syncthreads();
  if (t < 8){
    int glo = oc0/24, ghi = (oc0+63)/24;
    if (t >= glo && t <= ghi){
      atomicAdd(&stats[(b*8+t)*2],   (double)gsm[t*2]);
      atomicAdd(&stats[(b*8+t)*2+1], (double)gsm[t*2+1]);
    }
  }
}

// ---------------- GN apply + SiLU : bf16 in -> bf16 NHWC (for conv2) ----------------
__global__ __launch_bounds__(256) void k_gn1_apply(const unsigned short* __restrict__ x, const double* __restrict__ stats,
    const float* __restrict__ gs, const float* __restrict__ gb, unsigned short* __restrict__ y)
{
  size_t i8 = ((size_t)blockIdx.x*256 + threadIdx.x)*8;
  int b = (int)(i8 / ((size_t)192*P_));
  int c = (int)(i8 % 192);
  int bg = b*8 + c/24;
  const double N = 24.0*65536.0;
  double mu = stats[bg*2]/N;
  double var = stats[bg*2+1]/N - mu*mu;
  float rstd = 1.0f/sqrtf((float)var + 1e-5f);
  float mean = (float)mu;
  float4 sA = *(const float4*)&gs[c];
  float4 sB = *(const float4*)&gs[c+4];
  float4 bA = *(const float4*)&gb[c];
  float4 bB = *(const float4*)&gb[c+4];
  uint4 vv = *(const uint4*)&x[i8];
  unsigned wd[4] = {vv.x,vv.y,vv.z,vv.w};
  float scl[8] = {sA.x,sA.y,sA.z,sA.w,sB.x,sB.y,sB.z,sB.w};
  float bia[8] = {bA.x,bA.y,bA.z,bA.w,bB.x,bB.y,bB.z,bB.w};
  unsigned short h[8];
  #pragma unroll
  for (int i=0;i<8;i++){
    unsigned bits = wd[i>>1];
    float xi = (i&1) ? __uint_as_float(bits & 0xffff0000u) : __uint_as_float(bits<<16);
    float xn = (xi-mean)*rstd*scl[i] + bia[i];
    h[i] = f2bf(xn*sigmoidf_(xn));
  }
  *(uint4*)&y[i8] = *(uint4*)h;
}

// ---------------- GN apply + SiLU in place bf16 (h2) + fused global-avg-pool ----------------
__global__ __launch_bounds__(256) void k_gn2_apply(unsigned short* __restrict__ x, const double* __restrict__ stats,
    const float* __restrict__ gs, const float* __restrict__ gb, float* __restrict__ pooled)
{
  __shared__ float pl[384];
  int t = threadIdx.x;
  for (int f=t; f<384; f+=256) pl[f]=0.f;
  int tid = blockIdx.x*256 + t;
  int c = (tid*8) % 192;
  float4 sA = *(const float4*)&gs[c];
  float4 sB = *(const float4*)&gs[c+4];
  float4 bA = *(const float4*)&gb[c];
  float4 bB = *(const float4*)&gb[c+4];
  float scl[8] = {sA.x,sA.y,sA.z,sA.w,sB.x,sB.y,sB.z,sB.w};
  float bia[8] = {bA.x,bA.y,bA.z,bA.w,bB.x,bB.y,bB.z,bB.w};
  float mean[2], rstd[2];
  #pragma unroll
  for (int bb=0;bb<2;bb++){
    int bg = bb*8 + c/24;
    const double N = 24.0*65536.0;
    double mu = stats[bg*2]/N;
    double var = stats[bg*2+1]/N - mu*mu;
    rstd[bb] = 1.0f/sqrtf((float)var + 1e-5f);
    mean[bb] = (float)mu;
  }
  float pacc[2][8] = {{0.f}};
  __syncthreads();
  #pragma unroll
  for (int k=0;k<8;k++){
    size_t i8 = ((size_t)tid + (size_t)k*393216)*8;
    int bb = k>>2;
    uint4 vv = *(const uint4*)&x[i8];
    unsigned wd[4] = {vv.x,vv.y,vv.z,vv.w};
    unsigned short h[8];
    #pragma unroll
    for (int i=0;i<8;i++){
      unsigned bits = wd[i>>1];
      float xi = (i&1) ? __uint_as_float(bits & 0xffff0000u) : __uint_as_float(bits<<16);
      float xn = (xi-mean[bb])*rstd[bb]*scl[i] + bia[i];
      xn = xn*sigmoidf_(xn);
      h[i] = f2bf(xn);
      pacc[bb][i] += bf2f(h[i]);
    }
    *(uint4*)&x[i8] = *(uint4*)h;
  }
  #pragma unroll
  for (int bb=0;bb<2;bb++)
    #pragma unroll
    for (int i=0;i<8;i++) atomicAdd(&pl[bb*192 + c + i], pacc[bb][i]);
  __syncthreads();
  for (int f=t; f<384; f+=256) atomicAdd(&pooled[f], pl[f]*(1.f/65536.f));
}

// ---------------- channel gate MLP ----------------
__global__ void k_gate(const float* __restrict__ pooled, const float* __restrict__ gw1,
    const float* __restrict__ gb1, const float* __restrict__ gw2, const float* __restrict__ gb2,
    float* __restrict__ gatef)
{
  __shared__ float hb[2*48];
  int t = threadIdx.x;
  if (t<96){
    int b=t/48, j=t%48;
    float a = gb1[j];
    for (int c=0;c<192;c++) a = fmaf(pooled[b*192+c], gw1[j*192+c], a);
    hb[t] = a*sigmoidf_(a);
  }
  __syncthreads();
  for (int i=t;i<384;i+=256){
    int b=i/192, c=i%192;
    float a = gb2[c];
    for (int j=0;j<48;j++) a = fmaf(hb[b*48+j], gw2[c*48+j], a);
    gatef[i] = 0.5f + sigmoidf_(a);
  }
}

// ---------------- 1x1 residual GEMM via MFMA + final mix ----------------
__global__ __launch_bounds__(256,4) void k_combine(const unsigned short* __restrict__ ctxb,
    const unsigned short* __restrict__ h2, const float* __restrict__ rpw, const float* __restrict__ rpb,
    const float* __restrict__ gatef, const float* __restrict__ conf_out,
    const float* __restrict__ rs, const float* __restrict__ mix, float* __restrict__ dout)
{
  __shared__ short s_x[256*32];   // 16 KB
  __shared__ short s_w[64*32];    // 4 KB
  int t = threadIdx.x;
  size_t p0 = (size_t)blockIdx.x*256;     // flat pixel index over b*P
  int oc0 = blockIdx.y*64, br = blockIdx.y;
  int wv = t>>6, lane = t&63, l15 = lane&15, quad = lane>>4;
  f32x4 acc[4][4];
  #pragma unroll
  for (int mt=0;mt<4;mt++){
    float4 bv = *(const float4*)&rpb[oc0 + mt*16 + quad*4];
    f32x4 iv; iv.x=bv.x; iv.y=bv.y; iv.z=bv.z; iv.w=bv.w;
    #pragma unroll
    for (int nt=0;nt<4;nt++) acc[mt][nt]=iv;
  }
  for (int ch=0; ch<7; ch++){
    int ic0 = ch*32;
    __syncthreads();
    for (int f=t; f<1024; f+=256){
      int icq = f&3, px = f>>2;
      uint4 v = *(const uint4*)&ctxb[(p0+px)*ICP1 + ic0 + icq*8];
      *(uint4*)&s_x[px*32 + ((icq ^ ((px>>1)&3)))*8] = v;
    }
    {
      int oc = t&63, icq = t>>6;
      unsigned short h[8];
      #pragma unroll
      for (int j=0;j<8;j++){
        int ic = ic0 + icq*8 + j;
        h[j] = (ic<194) ? f2bf(rpw[(size_t)(oc0+oc)*194 + ic]) : (unsigned short)0;
      }
      *(uint4*)&s_w[oc*32 + ((icq ^ ((oc>>1)&3)))*8] = *(uint4*)h;
    }
    __syncthreads();
    bf16x8 Af[4], Bf[4];
    #pragma unroll
    for (int mt=0;mt<4;mt++){
      int r = mt*16 + l15;
      Af[mt] = *(const bf16x8*)&s_w[r*32 + (((quad ^ ((r>>1)&3)))&3)*8];
    }
    #pragma unroll
    for (int nt=0;nt<4;nt++){
      int r = wv*64 + nt*16 + l15;
      Bf[nt] = *(const bf16x8*)&s_x[r*32 + (((quad ^ ((r>>1)&3)))&3)*8];
    }
    #pragma unroll
    for (int mt=0;mt<4;mt++)
      #pragma unroll
      for (int nt=0;nt<4;nt++)
        acc[mt][nt] = __builtin_amdgcn_mfma_f32_16x16x32_bf16(Af[mt], Bf[nt], acc[mt][nt], 0, 0, 0);
  }
  float trs = tanhf(rs[0]);
  float ms2 = tanhf(mix[0]);
  int b = (int)(p0 >> 16);
  #pragma unroll
  for (int mt=0;mt<4;mt++){
    int oc = oc0 + mt*16 + quad*4;
    int cc = oc & 63;
    float4 gv = *(const float4*)&gatef[b*192 + oc];
    #pragma unroll
    for (int nt=0;nt<4;nt++){
      size_t pf = p0 + wv*64 + nt*16 + l15;
      int p = (int)(pf & 65535);
      ushort4 fh = *(const ushort4*)&ctxb[pf*ICP1 + oc];
      ushort4 hh = *(const ushort4*)&h2[pf*192 + oc];
      float cf = conf_out[((size_t)(b*3+br))*P_ + p];
      size_t dst = (size_t)br*OUT_B + ((size_t)(b*64+cc))*P_ + p;
      dout[dst]            = bf2f(fh.x) + ms2*(bf2f(hh.x)*gv.x + trs*acc[mt][nt].x)*cf;
      dout[dst + P_]       = bf2f(fh.y) + ms2*(bf2f(hh.y)*gv.y + trs*acc[mt][nt].y)*cf;
      dout[dst + 2*P_]     = bf2f(fh.z) + ms2*(bf2f(hh.z)*gv.z + trs*acc[mt][nt].z)*cf;
      dout[dst + 3*P_]     = bf2f(fh.w) + ms2*(bf2f(hh.w)*gv.w + trs*acc[mt][nt].w)*cf;
    }
  }
}

extern "C" void kernel_launch(void* const* d_in, const int* in_sizes, int n_in,
                              void* d_out, int out_size, void* d_ws, size_t ws_size,
                              hipStream_t stream)
{
  const float* vf    = (const float*)d_in[0];
  const float* uvs   = (const float*)d_in[1];
  const float* masks = (const float*)d_in[2];
  const float* wg    = (const float*)d_in[3];
  const float* wb    = (const float*)d_in[4];
  const float* wh    = (const float*)d_in[5];
  const float* c1w = (const float*)d_in[7];
  const float* c1b = (const float*)d_in[8];
  const float* g1s = (const float*)d_in[9];
  const float* g1b = (const float*)d_in[10];
  const float* c2w = (const float*)d_in[11];
  const float* c2b = (const float*)d_in[12];
  const float* g2s = (const float*)d_in[13];
  const float* g2b = (const float*)d_in[14];
  const float* gw1 = (const float*)d_in[15];
  const float* gb1 = (const float*)d_in[16];
  const float* gw2 = (const float*)d_in[17];
  const float* gb2 = (const float*)d_in[18];
  const float* rpw = (const float*)d_in[19];
  const float* rpb = (const float*)d_in[20];
  const float* rs  = (const float*)d_in[21];
  const float* cw  = (const float*)d_in[22];
  const float* cb  = (const float*)d_in[23];
  const float* mix = (const float*)d_in[24];

  char* ws = (char*)d_ws;
  float*          accb  = (float*)(ws + OFF_ACC);
  float*          cntb  = (float*)(ws + OFF_CNT);
  unsigned short* ctxb  = (unsigned short*)(ws + OFF_CTXB);
  unsigned short* h1act = (unsigned short*)(ws + OFF_H1A);
  unsigned short* w1p   = (unsigned short*)(ws + OFF_W1);
  unsigned short* w2p   = (unsigned short*)(ws + OFF_W2);
  unsigned short* h1pre = (unsigned short*)(ws + OFF_ACC);   // bf16, reuses acc region
  unsigned short* h2    = (unsigned short*)(ws + OFF_ACC);   // bf16, reuses acc region
  double* stats1 = (double*)(ws + OFF_SM + SM_STATS1);
  double* stats2 = (double*)(ws + OFF_SM + SM_STATS2);
  int*    scale  = (int*)(ws + OFF_SM + SM_SCALE);
  float*  pooled = (float*)(ws + OFF_SM + SM_POOLED);
  float*  gatef  = (float*)(ws + OFF_SM + SM_GATE);
  float*  rawu   = (float*)(ws + OFF_SM + SM_RAWU);
  float*  confp  = (float*)(ws + OFF_SM + SM_CONFP);

  float* out = (float*)d_out;
  float* out_cov  = out + OUT_COV;
  float* out_unc  = out + OUT_UNC;
  float* out_conf = out + OUT_CONF;

  hipMemsetAsync(ws + OFF_ACC, 0, SZ_ACC + SZ_CNT, stream);
  hipMemsetAsync(ws + OFF_SM, 0, 8192, stream);

  k_prep<<<2808, 256, 0, stream>>>(c1w, c2w, w1p, w2p);
  k_fuse<<<4096, 256, 0, stream>>>(vf, uvs, masks, wg, wb, wh, accb, cntb);
  k_finalize<<<2048, 256, 0, stream>>>(accb, cntb, ctxb, out_cov, rawu, scale, cw, cb, confp);
  k_norm_unc<<<512, 256, 0, stream>>>(ctxb, scale, rawu, out_cov, out_unc, confp, cw, out_conf);
  k_conv3<ICP1,7><<<dim3(128,3,2), 512, 0, stream>>>(ctxb, w1p, c1b, h1pre, stats1);
  k_gn1_apply<<<12288, 256, 0, stream>>>(h1pre, stats1, g1s, g1b, h1act);
  k_conv3<ICP2,6><<<dim3(128,3,2), 512, 0, stream>>>(h1act, w2p, c2b, h2, stats2);
  k_gn2_apply<<<1536, 256, 0, stream>>>(h2, stats2, g2s, g2b, pooled);
  k_gate<<<1, 256, 0, stream>>>(pooled, gw1, gb1, gw2, gb2, gatef);
  k_combine<<<dim3(512,3), 256, 0, stream>>>(ctxb, h2, rpw, rpb, gatef, out_conf, rs, mix, out);
}

// Round 6
// 713.083 us; speedup vs baseline: 1.3566x; 1.3566x over previous
//
#include <hip/hip_runtime.h>
#include <math.h>

#define B_ 2
#define V_ 8
#define C_ 64
#define HW_ 16384
#define A_ 256
#define P_ 65536
#define CO_ 192
#define CPG_ 24
#define NG_ 8
#define ICP1 224
#define ICP2 192

// workspace layout (bytes)
#define OFF_ACC   0ull
#define SZ_ACC    (2ull*65536*192*4)          // 100,663,296 ; reused for h1pre (bf16) then h2 (bf16)
#define OFF_CNT   (OFF_ACC + SZ_ACC)
#define SZ_CNT    (2ull*3*65536*4)
#define OFF_CTXB  (OFF_CNT + SZ_CNT)          // ctx NHWC bf16, 224-ch padded
#define SZ_CTXB   (2ull*65536*224*2)
#define OFF_H1A   (OFF_CTXB + SZ_CTXB)        // h1 activated, NHWC bf16, 192 ch
#define SZ_H1A    (2ull*65536*192*2)
#define OFF_W1    (OFF_H1A + SZ_H1A)
#define SZ_W1     (9ull*192*224*2)
#define OFF_W2    (OFF_W1 + SZ_W1)
#define SZ_W2     (9ull*192*192*2)
#define OFF_SM    (OFF_W2 + SZ_W2 + 256)

// small-region offsets (within OFF_SM)
#define SM_STATS1 0
#define SM_STATS2 256
#define SM_SCALE  512
#define SM_POOLED 1024
#define SM_GATE   2560
#define SM_RAWU   8192
#define SM_CONFP  532480            // 3*2*65536*4 = 1.5 MB partial conf dots

// d_out offsets (floats)
#define OUT_B    8388608
#define OUT_COV  25165824
#define OUT_UNC  25296896
#define OUT_CONF 25427968

typedef __attribute__((ext_vector_type(4))) float f32x4;
typedef __attribute__((ext_vector_type(8))) short bf16x8;

__device__ __forceinline__ float sigmoidf_(float x){ return 1.f/(1.f+expf(-x)); }
__device__ __forceinline__ float bf2f(unsigned short h){ return __uint_as_float(((unsigned)h)<<16); }
__device__ __forceinline__ unsigned short f2bf(float f){
  unsigned u = __float_as_uint(f);
  return (unsigned short)((u + 0x7fffu + ((u>>16)&1u)) >> 16);
}

__device__ __forceinline__ void gl_lds16(const void* g, void* l){
  __builtin_amdgcn_global_load_lds((const __attribute__((address_space(1))) void*)g,
                                   (__attribute__((address_space(3))) void*)l, 16, 0, 0);
}

// ---------------- K1: weight prep (blocks >= 4096) + fused tri-branch scatter (blocks < 4096) ----------------
__global__ __launch_bounds__(256) void k_prep_fuse(
    const float* __restrict__ c1w, const float* __restrict__ c2w,
    unsigned short* __restrict__ w1p, unsigned short* __restrict__ w2p,
    const float* __restrict__ vf, const float* __restrict__ uvs, const float* __restrict__ masks,
    const float* __restrict__ wgp, const float* __restrict__ wbp, const float* __restrict__ whp,
    float* __restrict__ acc, float* __restrict__ cnt)
{
  __shared__ __align__(16) float sf[64*65];
  __shared__ int sidx[64];
  __shared__ int svalid[64];
  __shared__ float sw[3];
  int t = threadIdx.x;
  int bid = blockIdx.x;
  if (bid >= 4096){
    // ---- weight prep branch ----
    int idx = (bid-4096)*256 + t;
    const int N1 = 9*192*224;
    if (idx < N1){
      int ic = idx % 224; int oc = (idx/224) % 192; int k = idx/(224*192);
      float v = (ic < 194) ? c1w[(size_t)(oc*194+ic)*9 + k] : 0.f;
      w1p[idx] = f2bf(v);
    } else {
      int i2 = idx - N1;
      if (i2 < 9*192*192){
        int ic = i2 % 192; int oc = (i2/192) % 192; int k = i2/(192*192);
        w2p[i2] = f2bf(c2w[(size_t)(oc*192+ic)*9 + k]);
      }
    }
    return;
  }
  // ---- fuse branch ----
  int pix0 = bid*64;
  int b   = pix0 / (V_*HW_);
  int rem = pix0 % (V_*HW_);
  int v   = rem / HW_;
  int p2  = rem % HW_;
  size_t vbase = ((size_t)(b*V_+v))*C_*HW_;
  // float4 global loads (1024 xfers), scalar LDS writes keep stride-65 conflict-free reads
  for (int i=0;i<4;i++){
    int f = t + i*256;
    int c = f>>4, px4 = (f&15)*4;
    float4 vv = *(const float4*)&vf[vbase + (size_t)c*HW_ + p2 + px4];
    float* d = &sf[c*65+px4];
    d[0]=vv.x; d[1]=vv.y; d[2]=vv.z; d[3]=vv.w;
  }
  if (t<64){
    const float* u2 = uvs + (((size_t)(b*V_+v))*HW_ + p2 + t)*2;
    float ux = u2[0], uy = u2[1];
    int fin = isfinite(ux) && isfinite(uy);
    float su = fin?ux:0.f, svv = fin?uy:0.f;
    float cu = fminf(fmaxf(su,0.f),1.f);
    float cv = fminf(fmaxf(svv,0.f),1.f);
    int xi = (int)rintf(cu*255.f);
    int yi = (int)rintf((1.f-cv)*255.f);
    sidx[t] = yi*256+xi;
    float m = masks[((size_t)(b*V_+v))*HW_ + p2 + t];
    svalid[t] = (m>0.5f) && fin;
  }
  if (t<3){
    const float* wp = (t==0)?wgp:((t==1)?wbp:whp);
    sw[t] = fmaxf(wp[b*V_+v], 0.f);
  }
  __syncthreads();
  int wave = t>>6, lane = t&63;
  float w0 = sw[0], w1 = sw[1], w2 = sw[2];
  for (int i=0;i<16;i++){
    int px = wave*16+i;
    if (!svalid[px]) continue;
    int bin = sidx[px];
    float val = sf[lane*65+px];
    size_t base = ((size_t)b*P_ + bin)*192;
    if (w0>0.f) atomicAdd(&acc[base + lane],        val*w0);
    if (w1>0.f) atomicAdd(&acc[base + 64 + lane],   val*w1);
    if (w2>0.f) atomicAdd(&acc[base + 128 + lane],  val*w2);
    if (lane<3){
      float wv = sw[lane];
      if (wv>0.f) atomicAdd(&cnt[((size_t)(b*3+lane))*P_ + bin], wv);
    }
  }
}

// ---------------- K2: finalize atlases -> ctx bf16 NHWC, coverage, raw unc, conf partial ----------------
__global__ __launch_bounds__(256) void k_finalize(const float* __restrict__ acc,
      const float* __restrict__ cnt, unsigned short* __restrict__ ctxb,
      float* __restrict__ out_cov, float* __restrict__ raw_unc, int* __restrict__ scale,
      const float* __restrict__ cw, const float* __restrict__ cbias, float* __restrict__ confp)
{
  __shared__ __align__(16) float sv[64*193];
  __shared__ float sc[3][64];
  __shared__ float up[256];
  __shared__ float up3[3][256];
  __shared__ float s_cov[64];
  __shared__ float s_unc[64];
  __shared__ float scw[582];
  int t = threadIdx.x;
  int bin0 = blockIdx.x*64;
  int b = bin0 >> 16;
  int p0 = bin0 & 65535;
  size_t abase = ((size_t)b*P_ + p0)*192;
  for (int f=t; f<582; f+=256) scw[f] = cw[f];
  for (int i=0;i<48;i++){
    int f = t + i*256;
    int bl = f/192, c = f - bl*192;
    sv[bl*193+c] = acc[abase + f];
  }
  if (t<192){
    int br = t>>6, bl = t&63;
    sc[br][bl] = cnt[((size_t)(b*3+br))*P_ + p0 + bl];
  }
  __syncthreads();
  {
    int bl = t>>2, q = t&3;
    float dg = 1.f/fmaxf(sc[0][bl],1.f);
    float db = 1.f/fmaxf(sc[1][bl],1.f);
    float dh = 1.f/fmaxf(sc[2][bl],1.f);
    float s = 0.f;
    for (int j=0;j<16;j++){
      int c = q*16+j;
      float fg = sv[bl*193+c]*dg;
      float fb = sv[bl*193+64+c]*db;
      float fh = sv[bl*193+128+c]*dh;
      sv[bl*193+c]=fg; sv[bl*193+64+c]=fb; sv[bl*193+128+c]=fh;
      float m = (fg+fb+fh)*(1.f/3.f);
      float d0=fg-m, d1=fb-m, d2=fh-m;
      s += d0*d0+d1*d1+d2*d2;
    }
    up[t] = s;
  }
  __syncthreads();
  if (t<64){
    float tot = up[t*4]+up[t*4+1]+up[t*4+2]+up[t*4+3];
    float u = sqrtf(tot*(1.f/192.f));
    float vg = sc[0][t]>0.f?1.f:0.f;
    float vb = sc[1][t]>0.f?1.f:0.f;
    float vh = sc[2][t]>0.f?1.f:0.f;
    float cov = fminf(fmaxf((vg+vb+vh)*(1.f/3.f),0.f),1.f);
    s_cov[t] = cov; s_unc[t] = u;
    out_cov[(size_t)b*P_ + p0 + t] = cov;
    raw_unc[(size_t)b*P_ + p0 + t] = u;
    atomicMax(&scale[b], __float_as_int(u));
  }
  __syncthreads();
  // conf partial dot over 192 feat channels (fp32 — more accurate than bf16 ctx read)
  {
    int bl = t>>2, q = t&3;
    float q0=0.f,q1=0.f,q2=0.f;
    for (int j=0;j<16;j++){
      int c = q*16+j;
      float fg = sv[bl*193+c];
      float fb = sv[bl*193+64+c];
      float fh = sv[bl*193+128+c];
      q0 += fg*scw[c]     + fb*scw[64+c]     + fh*scw[128+c];
      q1 += fg*scw[194+c] + fb*scw[258+c]    + fh*scw[322+c];
      q2 += fg*scw[388+c] + fb*scw[452+c]    + fh*scw[516+c];
    }
    up3[0][t]=q0; up3[1][t]=q1; up3[2][t]=q2;
  }
  __syncthreads();
  if (t<64){
    float cov = s_cov[t];
    #pragma unroll
    for (int o=0;o<3;o++){
      float pdot = up3[o][t*4]+up3[o][t*4+1]+up3[o][t*4+2]+up3[o][t*4+3]
                 + cov*scw[o*194+192] + cbias[o];
      confp[((size_t)(b*3+o))*P_ + p0 + t] = pdot;
    }
  }
  // pack NHWC bf16: 64 px x 28 groups of 8 ch
  for (int f=t; f<1792; f+=256){
    int cg = f % 28, bl = f / 28;
    int c0 = cg*8;
    unsigned short h[8];
    #pragma unroll
    for (int j=0;j<8;j++){
      int c = c0+j;
      float vv;
      if (c < 192)      vv = sv[bl*193+c];
      else if (c==192)  vv = s_cov[bl];
      else if (c==193)  vv = s_unc[bl];
      else              vv = 0.f;
      h[j] = f2bf(vv);
    }
    *(uint4*)&ctxb[((size_t)b*P_ + p0 + bl)*ICP1 + c0] = *(uint4*)h;
  }
}

// ---------------- K3: normalize uncertainty + finish conf ----------------
__global__ __launch_bounds__(256) void k_norm_unc(unsigned short* __restrict__ ctxb,
    const int* __restrict__ scale, const float* __restrict__ raw_unc,
    const float* __restrict__ out_cov, float* __restrict__ out_unc,
    const float* __restrict__ confp, const float* __restrict__ cw, float* __restrict__ out_conf)
{
  int tid = blockIdx.x*256 + threadIdx.x;
  int b = tid >> 16, p = tid & 65535;
  float s = fmaxf(__int_as_float(scale[b]), 1e-6f);
  float u = raw_unc[tid];
  float cov = out_cov[tid];
  float un = fminf(fmaxf(u/s,0.f),1.f)*cov;
  out_unc[tid] = un;
  ctxb[(size_t)tid*ICP1 + 193] = f2bf(un);
  float w0 = cw[193], w1 = cw[387], w2 = cw[581];
  out_conf[((size_t)(b*3+0))*P_ + p] = sigmoidf_(confp[((size_t)(b*3+0))*P_ + p] + w0*un);
  out_conf[((size_t)(b*3+1))*P_ + p] = sigmoidf_(confp[((size_t)(b*3+1))*P_ + p] + w1*un);
  out_conf[((size_t)(b*3+2))*P_ + p] = sigmoidf_(confp[((size_t)(b*3+2))*P_ + p] + w2*un);
}

// ---------------- conv 3x3 via MFMA bf16 implicit GEMM, row-pair blocking ----------------
// v4 (PROVEN, reverted from v5 role-split regression): each block computes TWO output rows
// (y0, y0+1) x 64 oc x 256 px. 256 thr / 4 waves; per chunk stage 4 input rows, each feeds
// rowA (ky=j) and rowB (ky=j-1). Weights once per chunk (36.9KB, split wa/wb). Counted vmcnt
// 7/4/4/10 schedule. Output bf16 NHWC; GN stats fused in epilogue (fp32 accs).
template<int ICP, int CHUNKS>
__global__ __launch_bounds__(256,2) void k_conv3(const unsigned short* __restrict__ X,
    const unsigned short* __restrict__ Wp, const float* __restrict__ bias, unsigned short* __restrict__ Y,
    double* __restrict__ stats)
{
  __shared__ short s_in[2][258*32];   // 2 x 16512 B
  __shared__ short s_w[576*32];       // 36864 B : rows r = (ky*3+kx)*64 + oc
  __shared__ float sred[2][64];
  __shared__ float gsm[16];
  int t = threadIdx.x;
  // XCD swizzle over 768 blocks: each XCD owns a 16-ypair (32-row) band for all (b,oc)
  int f_ = blockIdx.x + 128*(blockIdx.y + 3*blockIdx.z);
  int xcd = f_ & 7; int g_ = f_ >> 3;
  int ypair = xcd*16 + (g_ & 15);
  int h_  = g_ >> 4;                  // 0..5
  int b   = h_ & 1;
  int oc0 = (h_ >> 1)*64;
  int y0  = ypair*2;                  // 0..254 even
  int wv = t>>6, lane = t&63, l15 = lane&15, quad = lane>>4;

  f32x4 accA[4][4], accB[4][4];
  #pragma unroll
  for (int mt=0;mt<4;mt++){
    float4 bv = *(const float4*)&bias[oc0 + mt*16 + quad*4];
    f32x4 iv; iv.x=bv.x; iv.y=bv.y; iv.z=bv.z; iv.w=bv.w;
    #pragma unroll
    for (int nt=0;nt<4;nt++){ accA[mt][nt]=iv; accB[mt][nt]=iv; }
  }

  const unsigned short* Xb = X + (size_t)b*P_*ICP;

  // zero edge px slots (xi=0, xi=257) in both buffers + stats LDS
  if (t < 128){
    int bufi = t>>6, j = t&63;
    int idx = (j<32) ? j : (257*32 + (j-32));
    s_in[bufi][idx] = 0;
  }
  if (t < 128) sred[t>>6][t&63] = 0.f;
  if (t < 16)  gsm[t] = 0.f;

  // issue one input row for stage (c2,j2): 4 gl_lds/thread, buffer = j2&1
  auto issue_input = [&](int c2, int j2){
    int gy = y0 - 1 + j2;
    gy = min(max(gy,0),255);          // clamp; garbage rows are compute-skipped
    const unsigned short* src = Xb + ((size_t)gy*256)*ICP + c2*32;
    short* dst = &s_in[j2&1][0];
    #pragma unroll
    for (int i=0;i<4;i++){
      int f = t + i*256;
      int xi = 1 + (f>>2), icq = f&3;
      int icg = icq ^ ((xi>>1)&3);
      gl_lds16(src + (size_t)(xi-1)*ICP + icg*8, dst + 32 + (size_t)f*8);
    }
  };
  // weights ky=0,1 (rows 0..383): 6 gl_lds/thread
  auto issue_wa = [&](int c2){
    int ic0n = c2*32;
    #pragma unroll
    for (int i=0;i<6;i++){
      int f = t + i*256;
      int oc = (f>>2)&63, icq = f&3;
      int r = i*64 + oc;
      int icg = icq ^ ((r>>1)&3);
      gl_lds16(Wp + ((size_t)(i*192) + oc0 + oc)*ICP + ic0n + icg*8, &s_w[(size_t)f*8]);
    }
  };
  // weights ky=2 (rows 384..575): 3 gl_lds/thread
  auto issue_wb = [&](int c2){
    int ic0n = c2*32;
    #pragma unroll
    for (int i=0;i<3;i++){
      int f = t + i*256;
      int oc = (f>>2)&63, icq = f&3;
      int r = (6+i)*64 + oc;
      int icg = icq ^ ((r>>1)&3);
      gl_lds16(Wp + ((size_t)((6+i)*192) + oc0 + oc)*ICP + ic0n + icg*8, &s_w[(size_t)(1536+f)*8]);
    }
  };

  // prologue: order matters for vmcnt counts: Wa(6), I0(4), Wb(3), I1(4)
  issue_wa(0);
  issue_input(0,0);
  issue_wb(0);
  issue_input(0,1);
  asm volatile("s_waitcnt lgkmcnt(0)" ::: "memory");   // edge-zero ds_writes committed

  for (int c=0; c<CHUNKS; ++c){
    #pragma unroll
    for (int j=0;j<4;++j){
      if (j==0)      asm volatile("s_waitcnt vmcnt(7)" ::: "memory");
      else if (j==1) asm volatile("s_waitcnt vmcnt(4)" ::: "memory");
      else if (j==2) asm volatile("s_waitcnt vmcnt(4)" ::: "memory");
      else {
        if (c==CHUNKS-1) asm volatile("s_waitcnt vmcnt(0)"  ::: "memory");
        else             asm volatile("s_waitcnt vmcnt(10)" ::: "memory");
      }
      __builtin_amdgcn_s_barrier();
      __builtin_amdgcn_sched_barrier(0);

      bool doA = (j<=2) && (y0 + j >= 1);          // gy = y0-1+j valid for rowA (ky=j)
      bool doB = (j>=1) && (y0 - 1 + j <= 255);    // gy valid for rowB (ky=j-1)
      const short* si = &s_in[j&1][0];
      if (doA || doB){
        #pragma unroll
        for (int kx=0;kx<3;kx++){
          bf16x8 Bf[4];
          #pragma unroll
          for (int nt=0;nt<4;nt++){
            int r = wv*64 + nt*16 + l15 + kx;
            Bf[nt] = *(const bf16x8*)&si[r*32 + ((quad ^ ((r>>1)&3)))*8];
          }
          if (doA){
            bf16x8 Af[4];
            #pragma unroll
            for (int mt=0;mt<4;mt++){
              int r = j*192 + kx*64 + mt*16 + l15;
              Af[mt] = *(const bf16x8*)&s_w[r*32 + ((quad ^ ((r>>1)&3)))*8];
            }
            #pragma unroll
            for (int mt=0;mt<4;mt++)
              #pragma unroll
              for (int nt=0;nt<4;nt++)
                accA[mt][nt] = __builtin_amdgcn_mfma_f32_16x16x32_bf16(Af[mt], Bf[nt], accA[mt][nt], 0, 0, 0);
          }
          if (doB){
            bf16x8 Af[4];
            #pragma unroll
            for (int mt=0;mt<4;mt++){
              int r = (j-1)*192 + kx*64 + mt*16 + l15;
              Af[mt] = *(const bf16x8*)&s_w[r*32 + ((quad ^ ((r>>1)&3)))*8];
            }
            #pragma unroll
            for (int mt=0;mt<4;mt++)
              #pragma unroll
              for (int nt=0;nt<4;nt++)
                accB[mt][nt] = __builtin_amdgcn_mfma_f32_16x16x32_bf16(Af[mt], Bf[nt], accB[mt][nt], 0, 0, 0);
          }
        }
      }
      __builtin_amdgcn_s_barrier();
      __builtin_amdgcn_sched_barrier(0);
      // issue slot (order fixed: weights before input)
      if (j==2 && c+1<CHUNKS) issue_wa(c+1);
      if (j==3 && c+1<CHUNKS) issue_wb(c+1);
      if (!(c==CHUNKS-1 && j>=2))
        issue_input(j>=2 ? c+1 : c, (j+2)&3);
    }
  }

  // C-write: rows y0 and y0+1, bf16 NHWC
  unsigned short* Yb = Y + (size_t)b*P_*192;
  #pragma unroll
  for (int mt=0;mt<4;mt++){
    int oc = oc0 + mt*16 + quad*4;
    #pragma unroll
    for (int nt=0;nt<4;nt++){
      int px = wv*64 + nt*16 + l15;
      f32x4 a = accA[mt][nt];
      ushort4 ha; ha.x=f2bf(a.x); ha.y=f2bf(a.y); ha.z=f2bf(a.z); ha.w=f2bf(a.w);
      *(ushort4*)&Yb[(size_t)(y0*256+px)*192 + oc] = ha;
      f32x4 bb = accB[mt][nt];
      ushort4 hb; hb.x=f2bf(bb.x); hb.y=f2bf(bb.y); hb.z=f2bf(bb.z); hb.w=f2bf(bb.w);
      *(ushort4*)&Yb[(size_t)((y0+1)*256+px)*192 + oc] = hb;
    }
  }

  // fused GN stats over both rows (fp32 accs): wave-reduce over l15, LDS atomics over waves,
  // per-group LDS reduce, per-group global double atomics.
  #pragma unroll
  for (int mt=0;mt<4;mt++)
    #pragma unroll
    for (int jj=0;jj<4;jj++){
      float v1 = accA[mt][0][jj]+accA[mt][1][jj]+accA[mt][2][jj]+accA[mt][3][jj]
               + accB[mt][0][jj]+accB[mt][1][jj]+accB[mt][2][jj]+accB[mt][3][jj];
      float v2 = accA[mt][0][jj]*accA[mt][0][jj]+accA[mt][1][jj]*accA[mt][1][jj]
               + accA[mt][2][jj]*accA[mt][2][jj]+accA[mt][3][jj]*accA[mt][3][jj]
               + accB[mt][0][jj]*accB[mt][0][jj]+accB[mt][1][jj]*accB[mt][1][jj]
               + accB[mt][2][jj]*accB[mt][2][jj]+accB[mt][3][jj]*accB[mt][3][jj];
      v1 += __shfl_xor(v1,1); v1 += __shfl_xor(v1,2); v1 += __shfl_xor(v1,4); v1 += __shfl_xor(v1,8);
      v2 += __shfl_xor(v2,1); v2 += __shfl_xor(v2,2); v2 += __shfl_xor(v2,4); v2 += __shfl_xor(v2,8);
      if (l15==0){
        int ocl = mt*16 + quad*4 + jj;
        atomicAdd(&sred[0][ocl], v1);
        atomicAdd(&sred[1][ocl], v2);
      }
    }
  __syncthreads();
  if (t < 64){
    int g = (oc0 + t)/24;
    atomicAdd(&gsm[g*2],   sred[0][t]);
    atomicAdd(&gsm[g*2+1], sred[1][t]);
  }
  __syncthreads();
  if (t < 8){
    int glo = oc0/24, ghi = (oc0+63)/24;
    if (t >= glo && t <= ghi){
      atomicAdd(&stats[(b*8+t)*2],   (double)gsm[t*2]);
      atomicAdd(&stats[(b*8+t)*2+1], (double)gsm[t*2+1]);
    }
  }
}

// ---------------- GN apply + SiLU : bf16 in -> bf16 NHWC (for conv2) ----------------
__global__ __launch_bounds__(256) void k_gn1_apply(const unsigned short* __restrict__ x, const double* __restrict__ stats,
    const float* __restrict__ gs, const float* __restrict__ gb, unsigned short* __restrict__ y)
{
  size_t i8 = ((size_t)blockIdx.x*256 + threadIdx.x)*8;
  int b = (int)(i8 / ((size_t)192*P_));
  int c = (int)(i8 % 192);
  int bg = b*8 + c/24;
  const double N = 24.0*65536.0;
  double mu = stats[bg*2]/N;
  double var = stats[bg*2+1]/N - mu*mu;
  float rstd = 1.0f/sqrtf((float)var + 1e-5f);
  float mean = (float)mu;
  float4 sA = *(const float4*)&gs[c];
  float4 sB = *(const float4*)&gs[c+4];
  float4 bA = *(const float4*)&gb[c];
  float4 bB = *(const float4*)&gb[c+4];
  uint4 vv = *(const uint4*)&x[i8];
  unsigned wd[4] = {vv.x,vv.y,vv.z,vv.w};
  float scl[8] = {sA.x,sA.y,sA.z,sA.w,sB.x,sB.y,sB.z,sB.w};
  float bia[8] = {bA.x,bA.y,bA.z,bA.w,bB.x,bB.y,bB.z,bB.w};
  unsigned short h[8];
  #pragma unroll
  for (int i=0;i<8;i++){
    unsigned bits = wd[i>>1];
    float xi = (i&1) ? __uint_as_float(bits & 0xffff0000u) : __uint_as_float(bits<<16);
    float xn = (xi-mean)*rstd*scl[i] + bia[i];
    h[i] = f2bf(xn*sigmoidf_(xn));
  }
  *(uint4*)&y[i8] = *(uint4*)h;
}

// ---------------- GN apply + SiLU in place bf16 (h2) + fused global-avg-pool ----------------
__global__ __launch_bounds__(256) void k_gn2_apply(unsigned short* __restrict__ x, const double* __restrict__ stats,
    const float* __restrict__ gs, const float* __restrict__ gb, float* __restrict__ pooled)
{
  __shared__ float pl[384];
  int t = threadIdx.x;
  for (int f=t; f<384; f+=256) pl[f]=0.f;
  int tid = blockIdx.x*256 + t;
  int c = (tid*8) % 192;
  float4 sA = *(const float4*)&gs[c];
  float4 sB = *(const float4*)&gs[c+4];
  float4 bA = *(const float4*)&gb[c];
  float4 bB = *(const float4*)&gb[c+4];
  float scl[8] = {sA.x,sA.y,sA.z,sA.w,sB.x,sB.y,sB.z,sB.w};
  float bia[8] = {bA.x,bA.y,bA.z,bA.w,bB.x,bB.y,bB.z,bB.w};
  float mean[2], rstd[2];
  #pragma unroll
  for (int bb=0;bb<2;bb++){
    int bg = bb*8 + c/24;
    const double N = 24.0*65536.0;
    double mu = stats[bg*2]/N;
    double var = stats[bg*2+1]/N - mu*mu;
    rstd[bb] = 1.0f/sqrtf((float)var + 1e-5f);
    mean[bb] = (float)mu;
  }
  float pacc[2][8] = {{0.f}};
  __syncthreads();
  #pragma unroll
  for (int k=0;k<8;k++){
    size_t i8 = ((size_t)tid + (size_t)k*393216)*8;
    int bb = k>>2;
    uint4 vv = *(const uint4*)&x[i8];
    unsigned wd[4] = {vv.x,vv.y,vv.z,vv.w};
    unsigned short h[8];
    #pragma unroll
    for (int i=0;i<8;i++){
      unsigned bits = wd[i>>1];
      float xi = (i&1) ? __uint_as_float(bits & 0xffff0000u) : __uint_as_float(bits<<16);
      float xn = (xi-mean[bb])*rstd[bb]*scl[i] + bia[i];
      xn = xn*sigmoidf_(xn);
      h[i] = f2bf(xn);
      pacc[bb][i] += bf2f(h[i]);
    }
    *(uint4*)&x[i8] = *(uint4*)h;
  }
  #pragma unroll
  for (int bb=0;bb<2;bb++)
    #pragma unroll
    for (int i=0;i<8;i++) atomicAdd(&pl[bb*192 + c + i], pacc[bb][i]);
  __syncthreads();
  for (int f=t; f<384; f+=256) atomicAdd(&pooled[f], pl[f]*(1.f/65536.f));
}

// ---------------- 1x1 residual GEMM via MFMA + final mix (gate MLP fused in prologue) ----------------
__global__ __launch_bounds__(256,4) void k_combine(const unsigned short* __restrict__ ctxb,
    const unsigned short* __restrict__ h2, const float* __restrict__ rpw, const float* __restrict__ rpb,
    const float* __restrict__ pooled, const float* __restrict__ gw1, const float* __restrict__ gb1,
    const float* __restrict__ gw2, const float* __restrict__ gb2,
    const float* __restrict__ conf_out,
    const float* __restrict__ rs, const float* __restrict__ mix, float* __restrict__ dout)
{
  __shared__ short s_x[256*32];   // 16 KB
  __shared__ short s_w[64*32];    // 4 KB
  __shared__ float shb[48];
  __shared__ float sgate[64];
  int t = threadIdx.x;
  size_t p0 = (size_t)blockIdx.x*256;     // flat pixel index over b*P
  int oc0 = blockIdx.y*64, br = blockIdx.y;
  int b = (int)(p0 >> 16);
  int wv = t>>6, lane = t&63, l15 = lane&15, quad = lane>>4;
  // ---- inline channel-gate MLP for this (b, oc0..oc0+63) ----
  if (t < 48){
    float a = gb1[t];
    for (int c=0;c<192;c++) a = fmaf(pooled[b*192+c], gw1[t*192+c], a);
    shb[t] = a*sigmoidf_(a);
  }
  __syncthreads();
  if (t < 64){
    int c = oc0 + t;
    float a = gb2[c];
    for (int j=0;j<48;j++) a = fmaf(shb[j], gw2[c*48+j], a);
    sgate[t] = 0.5f + sigmoidf_(a);
  }
  f32x4 acc[4][4];
  #pragma unroll
  for (int mt=0;mt<4;mt++){
    float4 bv = *(const float4*)&rpb[oc0 + mt*16 + quad*4];
    f32x4 iv; iv.x=bv.x; iv.y=bv.y; iv.z=bv.z; iv.w=bv.w;
    #pragma unroll
    for (int nt=0;nt<4;nt++) acc[mt][nt]=iv;
  }
  for (int ch=0; ch<7; ch++){
    int ic0 = ch*32;
    __syncthreads();
    for (int f=t; f<1024; f+=256){
      int icq = f&3, px = f>>2;
      uint4 v = *(const uint4*)&ctxb[(p0+px)*ICP1 + ic0 + icq*8];
      *(uint4*)&s_x[px*32 + ((icq ^ ((px>>1)&3)))*8] = v;
    }
    {
      int oc = t&63, icq = t>>6;
      unsigned short h[8];
      #pragma unroll
      for (int j=0;j<8;j++){
        int ic = ic0 + icq*8 + j;
        h[j] = (ic<194) ? f2bf(rpw[(size_t)(oc0+oc)*194 + ic]) : (unsigned short)0;
      }
      *(uint4*)&s_w[oc*32 + ((icq ^ ((oc>>1)&3)))*8] = *(uint4*)h;
    }
    __syncthreads();
    bf16x8 Af[4], Bf[4];
    #pragma unroll
    for (int mt=0;mt<4;mt++){
      int r = mt*16 + l15;
      Af[mt] = *(const bf16x8*)&s_w[r*32 + (((quad ^ ((r>>1)&3)))&3)*8];
    }
    #pragma unroll
    for (int nt=0;nt<4;nt++){
      int r = wv*64 + nt*16 + l15;
      Bf[nt] = *(const bf16x8*)&s_x[r*32 + (((quad ^ ((r>>1)&3)))&3)*8];
    }
    #pragma unroll
    for (int mt=0;mt<4;mt++)
      #pragma unroll
      for (int nt=0;nt<4;nt++)
        acc[mt][nt] = __builtin_amdgcn_mfma_f32_16x16x32_bf16(Af[mt], Bf[nt], acc[mt][nt], 0, 0, 0);
  }
  float trs = tanhf(rs[0]);
  float ms2 = tanhf(mix[0]);
  #pragma unroll
  for (int mt=0;mt<4;mt++){
    int oc = oc0 + mt*16 + quad*4;
    int cc = oc & 63;
    int go = mt*16 + quad*4;
    float4 gv = make_float4(sgate[go], sgate[go+1], sgate[go+2], sgate[go+3]);
    #pragma unroll
    for (int nt=0;nt<4;nt++){
      size_t pf = p0 + wv*64 + nt*16 + l15;
      int p = (int)(pf & 65535);
      ushort4 fh = *(const ushort4*)&ctxb[pf*ICP1 + oc];
      ushort4 hh = *(const ushort4*)&h2[pf*192 + oc];
      float cf = conf_out[((size_t)(b*3+br))*P_ + p];
      size_t dst = (size_t)br*OUT_B + ((size_t)(b*64+cc))*P_ + p;
      dout[dst]            = bf2f(fh.x) + ms2*(bf2f(hh.x)*gv.x + trs*acc[mt][nt].x)*cf;
      dout[dst + P_]       = bf2f(fh.y) + ms2*(bf2f(hh.y)*gv.y + trs*acc[mt][nt].y)*cf;
      dout[dst + 2*P_]     = bf2f(fh.z) + ms2*(bf2f(hh.z)*gv.z + trs*acc[mt][nt].z)*cf;
      dout[dst + 3*P_]     = bf2f(fh.w) + ms2*(bf2f(hh.w)*gv.w + trs*acc[mt][nt].w)*cf;
    }
  }
}

extern "C" void kernel_launch(void* const* d_in, const int* in_sizes, int n_in,
                              void* d_out, int out_size, void* d_ws, size_t ws_size,
                              hipStream_t stream)
{
  const float* vf    = (const float*)d_in[0];
  const float* uvs   = (const float*)d_in[1];
  const float* masks = (const float*)d_in[2];
  const float* wg    = (const float*)d_in[3];
  const float* wb    = (const float*)d_in[4];
  const float* wh    = (const float*)d_in[5];
  const float* c1w = (const float*)d_in[7];
  const float* c1b = (const float*)d_in[8];
  const float* g1s = (const float*)d_in[9];
  const float* g1b = (const float*)d_in[10];
  const float* c2w = (const float*)d_in[11];
  const float* c2b = (const float*)d_in[12];
  const float* g2s = (const float*)d_in[13];
  const float* g2b = (const float*)d_in[14];
  const float* gw1 = (const float*)d_in[15];
  const float* gb1 = (const float*)d_in[16];
  const float* gw2 = (const float*)d_in[17];
  const float* gb2 = (const float*)d_in[18];
  const float* rpw = (const float*)d_in[19];
  const float* rpb = (const float*)d_in[20];
  const float* rs  = (const float*)d_in[21];
  const float* cw  = (const float*)d_in[22];
  const float* cb  = (const float*)d_in[23];
  const float* mix = (const float*)d_in[24];

  char* ws = (char*)d_ws;
  float*          accb  = (float*)(ws + OFF_ACC);
  float*          cntb  = (float*)(ws + OFF_CNT);
  unsigned short* ctxb  = (unsigned short*)(ws + OFF_CTXB);
  unsigned short* h1act = (unsigned short*)(ws + OFF_H1A);
  unsigned short* w1p   = (unsigned short*)(ws + OFF_W1);
  unsigned short* w2p   = (unsigned short*)(ws + OFF_W2);
  unsigned short* h1pre = (unsigned short*)(ws + OFF_ACC);   // bf16, reuses acc region
  unsigned short* h2    = (unsigned short*)(ws + OFF_ACC);   // bf16, reuses acc region
  double* stats1 = (double*)(ws + OFF_SM + SM_STATS1);
  double* stats2 = (double*)(ws + OFF_SM + SM_STATS2);
  int*    scale  = (int*)(ws + OFF_SM + SM_SCALE);
  float*  pooled = (float*)(ws + OFF_SM + SM_POOLED);
  float*  rawu   = (float*)(ws + OFF_SM + SM_RAWU);
  float*  confp  = (float*)(ws + OFF_SM + SM_CONFP);

  float* out = (float*)d_out;
  float* out_cov  = out + OUT_COV;
  float* out_unc  = out + OUT_UNC;
  float* out_conf = out + OUT_CONF;

  hipMemsetAsync(ws + OFF_ACC, 0, SZ_ACC + SZ_CNT, stream);
  hipMemsetAsync(ws + OFF_SM, 0, 8192, stream);

  k_prep_fuse<<<6904, 256, 0, stream>>>(c1w, c2w, w1p, w2p,
                                        vf, uvs, masks, wg, wb, wh, accb, cntb);
  k_finalize<<<2048, 256, 0, stream>>>(accb, cntb, ctxb, out_cov, rawu, scale, cw, cb, confp);
  k_norm_unc<<<512, 256, 0, stream>>>(ctxb, scale, rawu, out_cov, out_unc, confp, cw, out_conf);
  k_conv3<ICP1,7><<<dim3(128,3,2), 256, 0, stream>>>(ctxb, w1p, c1b, h1pre, stats1);
  k_gn1_apply<<<12288, 256, 0, stream>>>(h1pre, stats1, g1s, g1b, h1act);
  k_conv3<ICP2,6><<<dim3(128,3,2), 256, 0, stream>>>(h1act, w2p, c2b, h2, stats2);
  k_gn2_apply<<<1536, 256, 0, stream>>>(h2, stats2, g2s, g2b, pooled);
  k_combine<<<dim3(512,3), 256, 0, stream>>>(ctxb, h2, rpw, rpb, pooled, gw1, gb1, gw2, gb2,
                                             out_conf, rs, mix, out);
}